// Round 22
// baseline (243.587 us; speedup 1.0000x reference)
//
#include <hip/hip_runtime.h>
#include <hip/hip_bf16.h>
#include <cstdint>

#define T_TOK 8192
#define H_DIM 2048
#define N_EXP 8
#define FLAGBIT 0x80000000u

typedef __attribute__((ext_vector_type(4))) float f32x4;
typedef __attribute__((ext_vector_type(8))) short bf16x8;

__device__ __forceinline__ unsigned short f2bf(float f) {
  unsigned int u = __builtin_bit_cast(unsigned int, f);
  u += 0x7fffu + ((u >> 16) & 1u);  // RNE
  return (unsigned short)(u >> 16);
}

__device__ __forceinline__ unsigned cvtpk(float lo, float hi) {
  unsigned r;
  asm("v_cvt_pk_bf16_f32 %0, %1, %2" : "=v"(r) : "v"(lo), "v"(hi));
  return r;
}

#define GLL(SRC, DST) __builtin_amdgcn_global_load_lds( \
    (const __attribute__((address_space(1))) void*)(SRC), \
    (__attribute__((address_space(3))) void*)(DST), 16, 0, 0)

// ---- fused pre (r21): blocks <512 = router; >=512 = W f32->bf16 GLL conv ----
__global__ __launch_bounds__(256) void k_pre(const float* __restrict__ x,
    const float* __restrict__ wr, const float* __restrict__ we,
    unsigned short* __restrict__ xb, unsigned short* __restrict__ wb,
    int* __restrict__ idx)
{
  __shared__ char smem[65536];
  const int bid = blockIdx.x;
  if (bid >= 512) {
    auto* LDS3 = (__attribute__((address_space(3))) char*)smem;
    const char* LP = (const char*)smem;
    const int wv = threadIdx.x >> 6, l = threadIdx.x & 63;
    const size_t base = (size_t)(bid - 512) * 131072;
    const char* src = (const char*)we + base + wv * 8192 + l * 16;
    unsigned short* dstp = wb + (base >> 2) + wv * 2048 + l * 4;
#pragma unroll
    for (int i = 0; i < 8; ++i)
      GLL(src + i * 1024, LDS3 + wv * 8192 + i * 1024);
    for (int c = 0; c < 4; ++c) {
      const int b = (c & 1) * 32768;
      if (c < 3) {
        const char* s2 = src + (c + 1) * 32768;
        auto* d2 = LDS3 + (b ^ 32768) + wv * 8192;
#pragma unroll
        for (int i = 0; i < 8; ++i) GLL(s2 + i * 1024, d2 + i * 1024);
        asm volatile("s_waitcnt vmcnt(8)" ::: "memory");
      } else {
        asm volatile("s_waitcnt vmcnt(0)" ::: "memory");
      }
#pragma unroll
      for (int i = 0; i < 8; ++i) {
        const f32x4 v = *reinterpret_cast<const f32x4*>(LP + b + wv * 8192 + i * 1024 + l * 16);
        uint2 r;
        r.x = cvtpk(v[0], v[1]);
        r.y = cvtpk(v[2], v[3]);
        *reinterpret_cast<uint2*>(dstp + c * 8192 + i * 256) = r;
      }
    }
    return;
  }
  float* swr = (float*)smem;  // 64 KB
#pragma unroll
  for (int i = 0; i < 16; ++i) {
    const int o = (threadIdx.x + i * 256) * 4;
    *reinterpret_cast<float4*>(&swr[o]) = *reinterpret_cast<const float4*>(&wr[o]);
  }
  __syncthreads();
  const int wv = threadIdx.x >> 6, lane = threadIdx.x & 63;
  const int t0 = (bid * 4 + wv) * 4;
  float acc[4][N_EXP];
#pragma unroll
  for (int tt = 0; tt < 4; ++tt)
#pragma unroll
    for (int e = 0; e < N_EXP; ++e) acc[tt][e] = 0.f;
#pragma unroll
  for (int c = 0; c < H_DIM / 256; ++c) {
    const int h = c * 256 + lane * 4;
    float4 wvv[N_EXP];
#pragma unroll
    for (int e = 0; e < N_EXP; ++e)
      wvv[e] = *reinterpret_cast<const float4*>(&swr[e * H_DIM + h]);
#pragma unroll
    for (int tt = 0; tt < 4; ++tt) {
      const float4 xv = *reinterpret_cast<const float4*>(x + (size_t)(t0 + tt) * H_DIM + h);
      ushort4 bv;
      bv.x = f2bf(xv.x); bv.y = f2bf(xv.y); bv.z = f2bf(xv.z); bv.w = f2bf(xv.w);
      *reinterpret_cast<ushort4*>(xb + (size_t)(t0 + tt) * H_DIM + h) = bv;
#pragma unroll
      for (int e = 0; e < N_EXP; ++e) {
        acc[tt][e] = fmaf(xv.x, wvv[e].x, acc[tt][e]);
        acc[tt][e] = fmaf(xv.y, wvv[e].y, acc[tt][e]);
        acc[tt][e] = fmaf(xv.z, wvv[e].z, acc[tt][e]);
        acc[tt][e] = fmaf(xv.w, wvv[e].w, acc[tt][e]);
      }
    }
  }
#pragma unroll
  for (int off = 32; off >= 1; off >>= 1)
#pragma unroll
    for (int tt = 0; tt < 4; ++tt)
#pragma unroll
      for (int e = 0; e < N_EXP; ++e) acc[tt][e] += __shfl_xor(acc[tt][e], off, 64);
  if (lane == 0) {
#pragma unroll
    for (int tt = 0; tt < 4; ++tt) {
      float best = acc[tt][0]; int be = 0;
#pragma unroll
      for (int e = 1; e < N_EXP; ++e) if (acc[tt][e] > best) { best = acc[tt][e]; be = e; }
      idx[t0 + tt] = be;
    }
  }
}

// ---- fused sort (r11) ----
__global__ __launch_bounds__(1024) void k_sort(const int* __restrict__ idx,
    int* __restrict__ tlist, int* __restrict__ estar, int* __restrict__ mlo,
    int* __restrict__ mhi, int* __restrict__ rpos, int* __restrict__ rtile,
    int* __restrict__ rtc)
{
  __shared__ int wc[N_EXP][128];
  __shared__ int wbase[N_EXP][128];
  __shared__ int sTot[N_EXP];
  __shared__ int off[N_EXP + 1];
  __shared__ int sE[32], sCnt[N_EXP], sBase[N_EXP];
  const int tid = threadIdx.x, w = tid >> 6, l = tid & 63;
  int myE[8];
#pragma unroll
  for (int j = 0; j < 8; ++j) {
    myE[j] = idx[j * 1024 + tid];
#pragma unroll
    for (int e = 0; e < N_EXP; ++e) {
      const unsigned long long bm = __ballot(myE[j] == e);
      if (l == e) wc[e][j * 16 + w] = __popcll(bm);
    }
  }
  __syncthreads();
  if (tid < N_EXP) {
    int s = 0;
    for (int k = 0; k < 128; ++k) { wbase[tid][k] = s; s += wc[tid][k]; }
    sTot[tid] = s;
  }
  __syncthreads();
  if (tid == 0) {
    off[0] = 0;
    for (int e = 0; e < N_EXP; ++e) off[e + 1] = off[e] + sTot[e];
  }
  __syncthreads();
#pragma unroll
  for (int j = 0; j < 8; ++j) {
    int rank = 0;
#pragma unroll
    for (int e = 0; e < N_EXP; ++e) {
      const unsigned long long bm = __ballot(myE[j] == e);
      if (myE[j] == e) rank = __popcll(bm & ((1ull << l) - 1ull));
    }
    tlist[off[myE[j]] + wbase[myE[j]][j * 16 + w] + rank] = j * 1024 + tid;
  }
  if (tid < 32) {
    const int lo = tid * 256, hi = lo + 256;
    int bl = -1, bE = 0, bLo = 0, bHi = 0;
#pragma unroll
    for (int e = 0; e < N_EXP; ++e) {
      const int a = off[e] > lo ? off[e] : lo;
      const int b = off[e + 1] < hi ? off[e + 1] : hi;
      if (b - a > bl) { bl = b - a; bE = e; bLo = a - lo; bHi = b - lo; }
    }
    sE[tid] = bE; estar[tid] = bE; mlo[tid] = bLo; mhi[tid] = bHi;
  }
  __syncthreads();
  if (tid < N_EXP) {
    int cnt = 0;
    for (int t = 0; t < 32; ++t) {
      if (sE[t] == tid) continue;
      const int lo = t * 256, hi = lo + 256;
      const int a = off[tid] > lo ? off[tid] : lo;
      const int b = off[tid + 1] < hi ? off[tid + 1] : hi;
      if (b > a) cnt += b - a;
    }
    sCnt[tid] = cnt;
  }
  __syncthreads();
  if (tid == 0) {
    int base = 0, ntile = 0;
    for (int e = 0; e < N_EXP; ++e) {
      sBase[e] = base;
      const int pt = (sCnt[e] + 127) >> 7;
      for (int k = 0; k < pt; ++k) rtile[ntile++] = e;
      base += pt << 7;
    }
    *rtc = ntile;
  }
  __syncthreads();
  if (tid < N_EXP && sCnt[tid] > 0) {
    int ptr = sBase[tid], firstp = -1;
    for (int t = 0; t < 32; ++t) {
      if (sE[t] == tid) continue;
      const int lo = t * 256, hi = lo + 256;
      const int a = off[tid] > lo ? off[tid] : lo;
      const int b = off[tid + 1] < hi ? off[tid + 1] : hi;
      for (int p = a; p < b; ++p) { if (firstp < 0) firstp = p; rpos[ptr++] = p; }
    }
    const int end = sBase[tid] + (((sCnt[tid] + 127) >> 7) << 7);
    for (; ptr < end; ++ptr) rpos[ptr] = (int)((unsigned)firstp | FLAGBIT);
  }
}

// ---- zero minority cells (atomicAdd base for split-K repair) ----
__global__ __launch_bounds__(256) void k_zero_min(const int* __restrict__ rpos,
    const int* __restrict__ tlist, const int* __restrict__ rtc,
    float* __restrict__ out)
{
  const int nslots = (*rtc) << 7;
  const float4 z = {0.f, 0.f, 0.f, 0.f};
  for (int s = blockIdx.x; s < nslots; s += 256) {
    const int ent = rpos[s];
    if ((unsigned)ent & FLAGBIT) continue;
    const int tok = tlist[ent];
    float* op = out + (size_t)tok * H_DIM;
    for (int i = threadIdx.x; i < H_DIM / 4; i += 256)
      reinterpret_cast<float4*>(op)[i] = z;
  }
}

// ---- merged: blocks <1024 = main 128x128 GEMM (4 waves, BK=32, quad-buf 64KB
//      => 2 blocks/CU: cross-block stall hiding, m114); blocks >=1024 = repair
//      (4 waves, 128x256, split-K(2), atomicAdd onto zeroed cells). ----
__global__ __launch_bounds__(256) void k_gemm(const unsigned short* __restrict__ xb,
    const unsigned short* __restrict__ wb, const int* __restrict__ tlist,
    const int* __restrict__ estar, const int* __restrict__ mlo, const int* __restrict__ mhi,
    const int* __restrict__ rpos, const int* __restrict__ rtile, const int* __restrict__ rtc,
    float* __restrict__ out)
{
  __shared__ short lds[32768];  // 64 KiB: main 4x16KB quad-buf; repair A8K+B16K
  const int bid = blockIdx.x;
  const int tid = threadIdx.x;
  const int l = tid & 63, wv = tid >> 6;       // 4 waves
  const int l16 = l & 15, g16 = l >> 4;
  const char* LP = (const char*)lds;
  auto* LDS3 = (__attribute__((address_space(3))) char*)lds;
  const int csrc = ((l & 3) ^ ((l >> 3) & 3)) * 8;  // staging src chunk (elems)
  const int ch = (g16 ^ ((l16 >> 1) & 3)) << 4;     // read chunk (bytes)

  if (bid < 1024) {
    // ---------------- main: 128x128, XCD map, per-128 ownership ----------------
    const int idx8 = bid >> 3;
    const int mt = (bid & 7) * 8 + (idx8 >> 4);      // 64 m-tiles of 128 rows
    const int nt = idx8 & 15;                        // 16 n-tiles of 128 cols
    const int m0 = mt * 128, f0 = nt * 128;
    const int par = mt >> 1, half = (mt & 1) * 128;
    const int e = estar[par];
    const int mLo = mlo[par] - half, mHi = mhi[par] - half;  // local [0,128) clamp via compare
    const int wm = wv >> 1, wn = wv & 1;             // 2x2 waves, 64x64 out each

    const int aRd = (wm * 64 + l16) * 64 + ch;       // + mf*1024 imm
    const int bRd = 8192 + (wn * 64 + l16) * 64 + ch;

    // staging: per wave 2 A-GLLs + 2 B-GLLs per tile; GLL j covers rows wv*32+j*16+(l>>2)
    const int srow = l >> 2;
    const unsigned short* aS[2];
#pragma unroll
    for (int j = 0; j < 2; ++j) {
      const int tok = tlist[m0 + wv * 32 + j * 16 + srow];
      aS[j] = xb + (size_t)tok * H_DIM + csrc;
    }
    const unsigned short* bS[2];
#pragma unroll
    for (int j = 0; j < 2; ++j)
      bS[j] = wb + (size_t)e * H_DIM * H_DIM
                 + (size_t)(f0 + wv * 32 + j * 16 + srow) * H_DIM + csrc;
    const int dA0 = wv * 2048, dA1 = wv * 2048 + 1024;          // + buf*16384
    const int dB0 = 8192 + wv * 2048, dB1 = 8192 + wv * 2048 + 1024;

    f32x4 acc[4][4];
#pragma unroll
    for (int mf = 0; mf < 4; ++mf)
#pragma unroll
      for (int nf = 0; nf < 4; ++nf) acc[mf][nf] = (f32x4){0.f, 0.f, 0.f, 0.f};

    // prologue: stage tiles 0,1,2 (4 GLLs each); vmcnt(8) retires tile0
#pragma unroll
    for (int t0i = 0; t0i < 3; ++t0i) {
      const int bb = t0i * 16384, kk = t0i * 32;
      GLL(aS[0] + kk, LDS3 + bb + dA0);  GLL(aS[1] + kk, LDS3 + bb + dA1);
      GLL(bS[0] + kk, LDS3 + bb + dB0);  GLL(bS[1] + kk, LDS3 + bb + dB1);
    }
    asm volatile("s_waitcnt vmcnt(8)" ::: "memory");
    __builtin_amdgcn_sched_barrier(0);
    __builtin_amdgcn_s_barrier();
    __builtin_amdgcn_sched_barrier(0);

    for (int t = 0; t < 64; ++t) {
      const int buf  = (t & 3) * 16384;
      const int nbuf = ((t + 3) & 3) * 16384;
      const int kk   = ((t + 3) & 63) * 32;
      bf16x8 af[4], bf[4];
#pragma unroll
      for (int mf = 0; mf < 4; ++mf)
        af[mf] = *reinterpret_cast<const bf16x8*>(LP + buf + aRd + mf * 1024);
#pragma unroll
      for (int nf = 0; nf < 4; ++nf)
        bf[nf] = *reinterpret_cast<const bf16x8*>(LP + buf + bRd + nf * 1024);
      GLL(aS[0] + kk, LDS3 + nbuf + dA0);  GLL(aS[1] + kk, LDS3 + nbuf + dA1);
      GLL(bS[0] + kk, LDS3 + nbuf + dB0);  GLL(bS[1] + kk, LDS3 + nbuf + dB1);
      __builtin_amdgcn_s_setprio(1);
#pragma unroll
      for (int mf = 0; mf < 4; ++mf)
#pragma unroll
        for (int nf = 0; nf < 4; ++nf)
          acc[mf][nf] = __builtin_amdgcn_mfma_f32_16x16x32_bf16(af[mf], bf[nf], acc[mf][nf], 0, 0, 0);
      __builtin_amdgcn_s_setprio(0);
      asm volatile("s_waitcnt vmcnt(8)" ::: "memory");
      __builtin_amdgcn_sched_barrier(0);
      __builtin_amdgcn_s_barrier();
      __builtin_amdgcn_sched_barrier(0);
    }

    // epilogue: C/D map col=lane&15, row=4*(lane>>4)+reg [m89]; minority -> repair
#pragma unroll
    for (int mf = 0; mf < 4; ++mf) {
#pragma unroll
      for (int r = 0; r < 4; ++r) {
        const int row = wm * 64 + mf * 16 + g16 * 4 + r;   // local 0..127
        if (row >= mLo && row < mHi) {
          const int t2 = tlist[m0 + row];
          float* op = out + (size_t)t2 * H_DIM + f0 + wn * 64 + l16;
#pragma unroll
          for (int nf = 0; nf < 4; ++nf) op[nf * 16] = acc[mf][nf][r];
        }
      }
    }
    return;
  }

  // ---------------- repair: 128x256, 4 waves, split-K(2), BK=32, atomicAdd ----------------
  const int bid2 = bid - 1024;           // [0,1024)
  const int bx = bid2 >> 4;              // 64 repair tiles
  if (bx >= *rtc) return;
  const int f0 = ((bid2 >> 1) & 7) * 256;
  const int kc = bid2 & 1;
  const int e = rtile[bx];
  const int wm = wv >> 1, wn = wv & 1;   // 2M x 2N waves, 64x128 out each
  const int srow = l >> 2;

  const unsigned short* aS[2];
#pragma unroll
  for (int j = 0; j < 2; ++j) {
    const int ent = rpos[bx * 128 + wv * 32 + j * 16 + srow];
    const int tok = tlist[ent & 0x7fffffff];
    aS[j] = xb + (size_t)tok * H_DIM + csrc;
  }
  const unsigned short* bS[4];
#pragma unroll
  for (int j = 0; j < 4; ++j)
    bS[j] = wb + (size_t)e * H_DIM * H_DIM
               + (size_t)(f0 + wv * 64 + j * 16 + srow) * H_DIM + csrc;

  f32x4 acc[4][8];
#pragma unroll
  for (int mf = 0; mf < 4; ++mf)
#pragma unroll
    for (int nf = 0; nf < 8; ++nf) acc[mf][nf] = (f32x4){0.f, 0.f, 0.f, 0.f};

  for (int it = 0; it < 32; ++it) {
    const int kk = kc * 1024 + it * 32;
    __syncthreads();
#pragma unroll
    for (int j = 0; j < 2; ++j) GLL(aS[j] + kk, LDS3 + wv * 2048 + j * 1024);
#pragma unroll
    for (int j = 0; j < 4; ++j) GLL(bS[j] + kk, LDS3 + 8192 + wv * 4096 + j * 1024);
    __syncthreads();
    bf16x8 af[4];
#pragma unroll
    for (int mf = 0; mf < 4; ++mf)
      af[mf] = *reinterpret_cast<const bf16x8*>(LP + (wm * 64 + mf * 16 + l16) * 64 + ch);
#pragma unroll
    for (int nf = 0; nf < 8; ++nf) {
      const bf16x8 b0 = *reinterpret_cast<const bf16x8*>(
          LP + 8192 + (wn * 128 + nf * 16 + l16) * 64 + ch);
#pragma unroll
      for (int mf = 0; mf < 4; ++mf)
        acc[mf][nf] = __builtin_amdgcn_mfma_f32_16x16x32_bf16(af[mf], b0, acc[mf][nf], 0, 0, 0);
    }
  }
#pragma unroll
  for (int mf = 0; mf < 4; ++mf) {
#pragma unroll
    for (int r = 0; r < 4; ++r) {
      const int row = wm * 64 + mf * 16 + g16 * 4 + r;
      const int ent = rpos[bx * 128 + row];
      if (!((unsigned)ent & FLAGBIT)) {
        const int tok = tlist[ent];
        float* op = out + (size_t)tok * H_DIM + f0 + wn * 128 + l16;
#pragma unroll
        for (int nf = 0; nf < 8; ++nf) atomicAdd(op + nf * 16, acc[mf][nf][r]);
      }
    }
  }
}

extern "C" void kernel_launch(void* const* d_in, const int* in_sizes, int n_in,
                              void* d_out, int out_size, void* d_ws, size_t ws_size,
                              hipStream_t stream) {
  const float* x  = (const float*)d_in[0];
  const float* wr = (const float*)d_in[1];
  const float* we = (const float*)d_in[2];
  float* out = (float*)d_out;

  char* p = (char*)d_ws;
  unsigned short* xb = (unsigned short*)p; p += (size_t)T_TOK * H_DIM * 2;          // 32 MB
  unsigned short* wb = (unsigned short*)p; p += (size_t)N_EXP * H_DIM * H_DIM * 2;  // 64 MB
  int* idx    = (int*)p; p += T_TOK * 4;
  int* tlist  = (int*)p; p += T_TOK * 4;
  int* rpos   = (int*)p; p += T_TOK * 4;
  int* estar  = (int*)p; p += 32 * 4;
  int* mlo    = (int*)p; p += 32 * 4;
  int* mhi    = (int*)p; p += 32 * 4;
  int* rtile  = (int*)p; p += 64 * 4;
  int* rtc    = (int*)p; p += 64;

  k_pre<<<512 + 1024, 256, 0, stream>>>(x, wr, we, xb, wb, idx);
  k_sort<<<1, 1024, 0, stream>>>(idx, tlist, estar, mlo, mhi, rpos, rtile, rtc);
  k_zero_min<<<256, 256, 0, stream>>>(rpos, tlist, rtc, out);
  k_gemm<<<1024 + 1024, 256, 0, stream>>>(xb, wb, tlist, estar, mlo, mhi, rpos, rtile, rtc, out);
}

// Round 23
// 184.007 us; speedup vs baseline: 1.3238x; 1.3238x over previous
//
#include <hip/hip_runtime.h>
#include <hip/hip_bf16.h>
#include <cstdint>

#define T_TOK 8192
#define H_DIM 2048
#define N_EXP 8
#define FLAGBIT 0x80000000u

typedef __attribute__((ext_vector_type(4))) float f32x4;
typedef __attribute__((ext_vector_type(8))) short bf16x8;

__device__ __forceinline__ unsigned short f2bf(float f) {
  unsigned int u = __builtin_bit_cast(unsigned int, f);
  u += 0x7fffu + ((u >> 16) & 1u);  // RNE
  return (unsigned short)(u >> 16);
}

__device__ __forceinline__ unsigned cvtpk(float lo, float hi) {
  unsigned r;
  asm("v_cvt_pk_bf16_f32 %0, %1, %2" : "=v"(r) : "v"(lo), "v"(hi));
  return r;
}

#define GLL(SRC, DST) __builtin_amdgcn_global_load_lds( \
    (const __attribute__((address_space(1))) void*)(SRC), \
    (__attribute__((address_space(3))) void*)(DST), 16, 0, 0)

// ---- fused pre: blocks <512 = router (wr in LDS, 4 tok/wave, atomic-free);
//      blocks >=512 = W f32->bf16 via GLL double buffer. ----
__global__ __launch_bounds__(256) void k_pre(const float* __restrict__ x,
    const float* __restrict__ wr, const float* __restrict__ we,
    unsigned short* __restrict__ xb, unsigned short* __restrict__ wb,
    int* __restrict__ idx)
{
  __shared__ char smem[65536];
  const int bid = blockIdx.x;
  if (bid >= 512) {
    auto* LDS3 = (__attribute__((address_space(3))) char*)smem;
    const char* LP = (const char*)smem;
    const int wv = threadIdx.x >> 6, l = threadIdx.x & 63;
    const size_t base = (size_t)(bid - 512) * 131072;
    const char* src = (const char*)we + base + wv * 8192 + l * 16;
    unsigned short* dstp = wb + (base >> 2) + wv * 2048 + l * 4;
#pragma unroll
    for (int i = 0; i < 8; ++i)
      GLL(src + i * 1024, LDS3 + wv * 8192 + i * 1024);
    for (int c = 0; c < 4; ++c) {
      const int b = (c & 1) * 32768;
      if (c < 3) {
        const char* s2 = src + (c + 1) * 32768;
        auto* d2 = LDS3 + (b ^ 32768) + wv * 8192;
#pragma unroll
        for (int i = 0; i < 8; ++i) GLL(s2 + i * 1024, d2 + i * 1024);
        asm volatile("s_waitcnt vmcnt(8)" ::: "memory");
      } else {
        asm volatile("s_waitcnt vmcnt(0)" ::: "memory");
      }
#pragma unroll
      for (int i = 0; i < 8; ++i) {
        const f32x4 v = *reinterpret_cast<const f32x4*>(LP + b + wv * 8192 + i * 1024 + l * 16);
        uint2 r;
        r.x = cvtpk(v[0], v[1]);
        r.y = cvtpk(v[2], v[3]);
        *reinterpret_cast<uint2*>(dstp + c * 8192 + i * 256) = r;
      }
    }
    return;
  }
  float* swr = (float*)smem;  // 64 KB
#pragma unroll
  for (int i = 0; i < 16; ++i) {
    const int o = (threadIdx.x + i * 256) * 4;
    *reinterpret_cast<float4*>(&swr[o]) = *reinterpret_cast<const float4*>(&wr[o]);
  }
  __syncthreads();
  const int wv = threadIdx.x >> 6, lane = threadIdx.x & 63;
  const int t0 = (bid * 4 + wv) * 4;
  float acc[4][N_EXP];
#pragma unroll
  for (int tt = 0; tt < 4; ++tt)
#pragma unroll
    for (int e = 0; e < N_EXP; ++e) acc[tt][e] = 0.f;
#pragma unroll
  for (int c = 0; c < H_DIM / 256; ++c) {
    const int h = c * 256 + lane * 4;
    float4 wvv[N_EXP];
#pragma unroll
    for (int e = 0; e < N_EXP; ++e)
      wvv[e] = *reinterpret_cast<const float4*>(&swr[e * H_DIM + h]);
#pragma unroll
    for (int tt = 0; tt < 4; ++tt) {
      const float4 xv = *reinterpret_cast<const float4*>(x + (size_t)(t0 + tt) * H_DIM + h);
      ushort4 bv;
      bv.x = f2bf(xv.x); bv.y = f2bf(xv.y); bv.z = f2bf(xv.z); bv.w = f2bf(xv.w);
      *reinterpret_cast<ushort4*>(xb + (size_t)(t0 + tt) * H_DIM + h) = bv;
#pragma unroll
      for (int e = 0; e < N_EXP; ++e) {
        acc[tt][e] = fmaf(xv.x, wvv[e].x, acc[tt][e]);
        acc[tt][e] = fmaf(xv.y, wvv[e].y, acc[tt][e]);
        acc[tt][e] = fmaf(xv.z, wvv[e].z, acc[tt][e]);
        acc[tt][e] = fmaf(xv.w, wvv[e].w, acc[tt][e]);
      }
    }
  }
#pragma unroll
  for (int off = 32; off >= 1; off >>= 1)
#pragma unroll
    for (int tt = 0; tt < 4; ++tt)
#pragma unroll
      for (int e = 0; e < N_EXP; ++e) acc[tt][e] += __shfl_xor(acc[tt][e], off, 64);
  if (lane == 0) {
#pragma unroll
    for (int tt = 0; tt < 4; ++tt) {
      float best = acc[tt][0]; int be = 0;
#pragma unroll
      for (int e = 1; e < N_EXP; ++e) if (acc[tt][e] > best) { best = acc[tt][e]; be = e; }
      idx[t0 + tt] = be;
    }
  }
}

// ---- fused sort (r11) ----
__global__ __launch_bounds__(1024) void k_sort(const int* __restrict__ idx,
    int* __restrict__ tlist, int* __restrict__ estar, int* __restrict__ mlo,
    int* __restrict__ mhi, int* __restrict__ rpos, int* __restrict__ rtile,
    int* __restrict__ rtc)
{
  __shared__ int wc[N_EXP][128];
  __shared__ int wbase[N_EXP][128];
  __shared__ int sTot[N_EXP];
  __shared__ int off[N_EXP + 1];
  __shared__ int sE[32], sCnt[N_EXP], sBase[N_EXP];
  const int tid = threadIdx.x, w = tid >> 6, l = tid & 63;
  int myE[8];
#pragma unroll
  for (int j = 0; j < 8; ++j) {
    myE[j] = idx[j * 1024 + tid];
#pragma unroll
    for (int e = 0; e < N_EXP; ++e) {
      const unsigned long long bm = __ballot(myE[j] == e);
      if (l == e) wc[e][j * 16 + w] = __popcll(bm);
    }
  }
  __syncthreads();
  if (tid < N_EXP) {
    int s = 0;
    for (int k = 0; k < 128; ++k) { wbase[tid][k] = s; s += wc[tid][k]; }
    sTot[tid] = s;
  }
  __syncthreads();
  if (tid == 0) {
    off[0] = 0;
    for (int e = 0; e < N_EXP; ++e) off[e + 1] = off[e] + sTot[e];
  }
  __syncthreads();
#pragma unroll
  for (int j = 0; j < 8; ++j) {
    int rank = 0;
#pragma unroll
    for (int e = 0; e < N_EXP; ++e) {
      const unsigned long long bm = __ballot(myE[j] == e);
      if (myE[j] == e) rank = __popcll(bm & ((1ull << l) - 1ull));
    }
    tlist[off[myE[j]] + wbase[myE[j]][j * 16 + w] + rank] = j * 1024 + tid;
  }
  if (tid < 32) {
    const int lo = tid * 256, hi = lo + 256;
    int bl = -1, bE = 0, bLo = 0, bHi = 0;
#pragma unroll
    for (int e = 0; e < N_EXP; ++e) {
      const int a = off[e] > lo ? off[e] : lo;
      const int b = off[e + 1] < hi ? off[e + 1] : hi;
      if (b - a > bl) { bl = b - a; bE = e; bLo = a - lo; bHi = b - lo; }
    }
    sE[tid] = bE; estar[tid] = bE; mlo[tid] = bLo; mhi[tid] = bHi;
  }
  __syncthreads();
  if (tid < N_EXP) {
    int cnt = 0;
    for (int t = 0; t < 32; ++t) {
      if (sE[t] == tid) continue;
      const int lo = t * 256, hi = lo + 256;
      const int a = off[tid] > lo ? off[tid] : lo;
      const int b = off[tid + 1] < hi ? off[tid + 1] : hi;
      if (b > a) cnt += b - a;
    }
    sCnt[tid] = cnt;
  }
  __syncthreads();
  if (tid == 0) {
    int base = 0, ntile = 0;
    for (int e = 0; e < N_EXP; ++e) {
      sBase[e] = base;
      const int pt = (sCnt[e] + 127) >> 7;
      for (int k = 0; k < pt; ++k) rtile[ntile++] = e;
      base += pt << 7;
    }
    *rtc = ntile;
  }
  __syncthreads();
  if (tid < N_EXP && sCnt[tid] > 0) {
    int ptr = sBase[tid], firstp = -1;
    for (int t = 0; t < 32; ++t) {
      if (sE[t] == tid) continue;
      const int lo = t * 256, hi = lo + 256;
      const int a = off[tid] > lo ? off[tid] : lo;
      const int b = off[tid + 1] < hi ? off[tid + 1] : hi;
      for (int p = a; p < b; ++p) { if (firstp < 0) firstp = p; rpos[ptr++] = p; }
    }
    const int end = sBase[tid] + (((sCnt[tid] + 127) >> 7) << 7);
    for (; ptr < end; ++ptr) rpos[ptr] = (int)((unsigned)firstp | FLAGBIT);
  }
}

// ---- zero minority cells (atomicAdd base for split-K repair) ----
__global__ __launch_bounds__(256) void k_zero_min(const int* __restrict__ rpos,
    const int* __restrict__ tlist, const int* __restrict__ rtc,
    float* __restrict__ out)
{
  const int nslots = (*rtc) << 7;
  const float4 z = {0.f, 0.f, 0.f, 0.f};
  for (int s = blockIdx.x; s < nslots; s += 256) {
    const int ent = rpos[s];
    if ((unsigned)ent & FLAGBIT) continue;
    const int tok = tlist[ent];
    float* op = out + (size_t)tok * H_DIM;
    for (int i = threadIdx.x; i < H_DIM / 4; i += 256)
      reinterpret_cast<float4*>(op)[i] = z;
  }
}

// ---- merged (r17): blocks <256 = main 16-wave GEMM (BK=32, quad-buf,
//      ONE barrier/phase); blocks 256..1279 = repair (split-K(2), atomicAdd) ----
__global__ __launch_bounds__(1024, 4) void k_gemm(const unsigned short* __restrict__ xb,
    const unsigned short* __restrict__ wb, const int* __restrict__ tlist,
    const int* __restrict__ estar, const int* __restrict__ mlo, const int* __restrict__ mhi,
    const int* __restrict__ rpos, const int* __restrict__ rtile, const int* __restrict__ rtc,
    float* __restrict__ out)
{
  __shared__ short lds[65536];  // 128 KiB = 4 x 32KB bufs (main) / 48KB (repair)
  const int bid = blockIdx.x;
  const int tid = threadIdx.x;
  const int l = tid & 63, wv = tid >> 6;       // 16 waves
  const int l16 = l & 15, g16 = l >> 4;
  const char* LP = (const char*)lds;
  auto* LDS3 = (__attribute__((address_space(3))) char*)lds;

  if (bid < 256) {
    const int mt = (bid & 7) * 4 + ((bid >> 3) & 3);  // XCD-locality map
    const int nt = bid >> 5;
    const int m0 = mt * 256, f0 = nt * 256;
    const int e = estar[mt], mLo = mlo[mt], mHi = mhi[mt];
    const int wm = wv >> 2, wn = wv & 3;       // 4M x 4N waves, 64x64 out each

    const int ch = (g16 ^ ((l16 >> 1) & 3)) << 4;
    const int aRd = (wm * 64 + l16) * 64 + ch;            // + mf*1024 imm
    const int bRd = 16384 + (wn * 64 + l16) * 64 + ch;    // + nf*1024 imm

    const int csrc = (((l & 3) ^ ((l >> 3) & 3))) * 8;
    const int srow = l >> 2;
    const int tokA = tlist[m0 + wv * 16 + srow];
    const unsigned short* aS = xb + (size_t)tokA * H_DIM + csrc;
    const unsigned short* bS = wb + (size_t)e * H_DIM * H_DIM
                                  + (size_t)(f0 + wv * 16 + srow) * H_DIM + csrc;
    const int dA = wv * 1024;             // + buf*32768
    const int dB = 16384 + wv * 1024;

    f32x4 acc[4][4];
#pragma unroll
    for (int mf = 0; mf < 4; ++mf)
#pragma unroll
      for (int nf = 0; nf < 4; ++nf) acc[mf][nf] = (f32x4){0.f, 0.f, 0.f, 0.f};

    // prologue: stage tiles 0,1,2 -> bufs 0,1,2; retire tile0 (vmcnt 4)
    GLL(aS +  0, LDS3 + 0 * 32768 + dA);  GLL(bS +  0, LDS3 + 0 * 32768 + dB);
    GLL(aS + 32, LDS3 + 1 * 32768 + dA);  GLL(bS + 32, LDS3 + 1 * 32768 + dB);
    GLL(aS + 64, LDS3 + 2 * 32768 + dA);  GLL(bS + 64, LDS3 + 2 * 32768 + dB);
    asm volatile("s_waitcnt vmcnt(4)" ::: "memory");
    __builtin_amdgcn_sched_barrier(0);
    __builtin_amdgcn_s_barrier();
    __builtin_amdgcn_sched_barrier(0);

    for (int t = 0; t < 64; ++t) {
      const int buf  = (t & 3) * 32768;
      const int nbuf = ((t + 3) & 3) * 32768;
      const int kk   = ((t + 3) & 63) * 32;
      bf16x8 af[4], bf[4];
#pragma unroll
      for (int mf = 0; mf < 4; ++mf)
        af[mf] = *reinterpret_cast<const bf16x8*>(LP + buf + aRd + mf * 1024);
#pragma unroll
      for (int nf = 0; nf < 4; ++nf)
        bf[nf] = *reinterpret_cast<const bf16x8*>(LP + buf + bRd + nf * 1024);
      GLL(aS + kk, LDS3 + nbuf + dA);
      GLL(bS + kk, LDS3 + nbuf + dB);
      __builtin_amdgcn_s_setprio(1);
#pragma unroll
      for (int mf = 0; mf < 4; ++mf)
#pragma unroll
        for (int nf = 0; nf < 4; ++nf)
          acc[mf][nf] = __builtin_amdgcn_mfma_f32_16x16x32_bf16(af[mf], bf[nf], acc[mf][nf], 0, 0, 0);
      __builtin_amdgcn_s_setprio(0);
      asm volatile("s_waitcnt vmcnt(4)" ::: "memory");
      __builtin_amdgcn_sched_barrier(0);
      __builtin_amdgcn_s_barrier();
      __builtin_amdgcn_sched_barrier(0);
    }

    // epilogue: C/D map col=lane&15, row=4*(lane>>4)+reg [m89]
#pragma unroll
    for (int mf = 0; mf < 4; ++mf) {
#pragma unroll
      for (int r = 0; r < 4; ++r) {
        const int row = wm * 64 + mf * 16 + g16 * 4 + r;
        if (row >= mLo && row < mHi) {
          const int t2 = tlist[m0 + row];
          float* op = out + (size_t)t2 * H_DIM + f0 + wn * 64 + l16;
#pragma unroll
          for (int nf = 0; nf < 4; ++nf) op[nf * 16] = acc[mf][nf][r];
        }
      }
    }
    return;
  }

  // ---------------- repair: 128x256 tile, 16 waves, split-K(2), atomicAdd ----------------
  const int bid2 = bid - 256;            // [0,1024)
  const int bx = bid2 >> 4;              // 64 repair tiles
  if (bx >= *rtc) return;
  const int f0 = ((bid2 >> 1) & 7) * 256;
  const int kc = bid2 & 1;
  const int e = rtile[bx];
  const int wm = wv >> 2, wn = wv & 3;   // 4M x 4N waves, 32x64 out each
  const int sw = l16 & 7;
  const int ch0 = ((0 + g16) ^ sw) << 4, ch1 = ((4 + g16) ^ sw) << 4;  // 128B rows
  const int csrc8 = ((l & 7) ^ ((l >> 3) & 7)) * 8;
  const int srow8 = l >> 3;

  const unsigned short* aS;
  {
    const int ent = rpos[bx * 128 + wv * 8 + srow8];
    const int tok = tlist[ent & 0x7fffffff];
    aS = xb + (size_t)tok * H_DIM + csrc8;
  }
  const unsigned short* bS0 = wb + (size_t)e * H_DIM * H_DIM
                                 + (size_t)(f0 + wv * 8 + srow8) * H_DIM + csrc8;
  const unsigned short* bS1 = bS0 + (size_t)128 * H_DIM;

  f32x4 acc[2][4];
#pragma unroll
  for (int mf = 0; mf < 2; ++mf)
#pragma unroll
    for (int nf = 0; nf < 4; ++nf) acc[mf][nf] = (f32x4){0.f, 0.f, 0.f, 0.f};

  for (int it = 0; it < 16; ++it) {
    const int kk = kc * 1024 + it * 64;
    __syncthreads();
    GLL(aS + kk, LDS3 + wv * 1024);                        // A 16KB @0
    GLL(bS0 + kk, LDS3 + 16384 + wv * 1024);               // B 32KB @16384
    GLL(bS1 + kk, LDS3 + 16384 + 16384 + wv * 1024);
    __syncthreads();
    bf16x8 af[2][2];
#pragma unroll
    for (int mf = 0; mf < 2; ++mf) {
      af[mf][0] = *reinterpret_cast<const bf16x8*>(LP + (wm * 32 + mf * 16 + l16) * 128 + ch0);
      af[mf][1] = *reinterpret_cast<const bf16x8*>(LP + (wm * 32 + mf * 16 + l16) * 128 + ch1);
    }
#pragma unroll
    for (int nf = 0; nf < 4; ++nf) {
      const bf16x8 b0 = *reinterpret_cast<const bf16x8*>(LP + 16384 + (wn * 64 + nf * 16 + l16) * 128 + ch0);
      const bf16x8 b1 = *reinterpret_cast<const bf16x8*>(LP + 16384 + (wn * 64 + nf * 16 + l16) * 128 + ch1);
#pragma unroll
      for (int mf = 0; mf < 2; ++mf) {
        acc[mf][nf] = __builtin_amdgcn_mfma_f32_16x16x32_bf16(af[mf][0], b0, acc[mf][nf], 0, 0, 0);
        acc[mf][nf] = __builtin_amdgcn_mfma_f32_16x16x32_bf16(af[mf][1], b1, acc[mf][nf], 0, 0, 0);
      }
    }
  }
#pragma unroll
  for (int mf = 0; mf < 2; ++mf) {
#pragma unroll
    for (int r = 0; r < 4; ++r) {
      const int row = wm * 32 + mf * 16 + g16 * 4 + r;
      const int ent = rpos[bx * 128 + row];
      if (!((unsigned)ent & FLAGBIT)) {
        const int tok = tlist[ent];
        float* op = out + (size_t)tok * H_DIM + f0 + wn * 64 + l16;
#pragma unroll
        for (int nf = 0; nf < 4; ++nf) atomicAdd(op + nf * 16, acc[mf][nf][r]);
      }
    }
  }
}

extern "C" void kernel_launch(void* const* d_in, const int* in_sizes, int n_in,
                              void* d_out, int out_size, void* d_ws, size_t ws_size,
                              hipStream_t stream) {
  const float* x  = (const float*)d_in[0];
  const float* wr = (const float*)d_in[1];
  const float* we = (const float*)d_in[2];
  float* out = (float*)d_out;

  char* p = (char*)d_ws;
  unsigned short* xb = (unsigned short*)p; p += (size_t)T_TOK * H_DIM * 2;          // 32 MB
  unsigned short* wb = (unsigned short*)p; p += (size_t)N_EXP * H_DIM * H_DIM * 2;  // 64 MB
  int* idx    = (int*)p; p += T_TOK * 4;
  int* tlist  = (int*)p; p += T_TOK * 4;
  int* rpos   = (int*)p; p += T_TOK * 4;
  int* estar  = (int*)p; p += 32 * 4;
  int* mlo    = (int*)p; p += 32 * 4;
  int* mhi    = (int*)p; p += 32 * 4;
  int* rtile  = (int*)p; p += 64 * 4;
  int* rtc    = (int*)p; p += 64;

  k_pre<<<512 + 1024, 256, 0, stream>>>(x, wr, we, xb, wb, idx);
  k_sort<<<1, 1024, 0, stream>>>(idx, tlist, estar, mlo, mhi, rpos, rtile, rtc);
  k_zero_min<<<256, 256, 0, stream>>>(rpos, tlist, rtc, out);
  k_gemm<<<256 + 1024, 1024, 0, stream>>>(xb, wb, tlist, estar, mlo, mhi, rpos, rtile, rtc, out);
}